// Round 1
// baseline (1101.533 us; speedup 1.0000x reference)
//
#include <hip/hip_runtime.h>
#include <hip/hip_bf16.h>

#define MASK_IDX 0

// Masked NLL: loss = sum_{i: tgt[i]!=0} -log(out[i*V + tgt[i]]) / count(tgt!=0)
// B*S = 8192 pairs, V = 32000. Single block, full reduction in one launch.
__global__ __launch_bounds__(1024) void nll_loss_kernel(
    const float* __restrict__ out,   // [BS, V]
    const int*   __restrict__ tgt,   // [BS]
    float* __restrict__ res,         // [1]
    int BS, int V)
{
    const int tid = threadIdx.x;

    float sum = 0.0f;
    float cnt = 0.0f;

    for (int i = tid; i < BS; i += blockDim.x) {
        int t = tgt[i];
        if (t != MASK_IDX) {
            float p = out[(long long)i * V + t];
            sum -= __builtin_logf(p);
            cnt += 1.0f;
        }
    }

    // wave (64-lane) butterfly reduce
    #pragma unroll
    for (int off = 32; off > 0; off >>= 1) {
        sum += __shfl_down(sum, off, 64);
        cnt += __shfl_down(cnt, off, 64);
    }

    __shared__ float ssum[16];
    __shared__ float scnt[16];
    const int wave = tid >> 6;
    const int lane = tid & 63;
    if (lane == 0) { ssum[wave] = sum; scnt[wave] = cnt; }
    __syncthreads();

    if (tid < 16) {
        sum = ssum[tid];
        cnt = scnt[tid];
        #pragma unroll
        for (int off = 8; off > 0; off >>= 1) {
            sum += __shfl_down(sum, off, 64);
            cnt += __shfl_down(cnt, off, 64);
        }
        if (tid == 0) {
            res[0] = sum / cnt;
        }
    }
}

extern "C" void kernel_launch(void* const* d_in, const int* in_sizes, int n_in,
                              void* d_out, int out_size, void* d_ws, size_t ws_size,
                              hipStream_t stream) {
    const float* out = (const float*)d_in[0];   // [B, S, V] fp32
    const int*   tgt = (const int*)d_in[1];     // [B, S] int32
    float* res = (float*)d_out;

    const int BS = in_sizes[1];                 // 16*512 = 8192
    const int V  = in_sizes[0] / in_sizes[1];   // 32000

    nll_loss_kernel<<<1, 1024, 0, stream>>>(out, tgt, res, BS, V);
}

// Round 2
// 1085.936 us; speedup vs baseline: 1.0144x; 1.0144x over previous
//
#include <hip/hip_runtime.h>
#include <hip/hip_bf16.h>

#define MASK_IDX 0

// Masked NLL: loss = sum_{i: tgt[i]!=0} -log(out[i*V + tgt[i]]) / count(tgt!=0)
// B*S = 8192 pairs, V = 32000.
//
// Stage 1: 128 blocks x 64 threads (one wave/block), one (b,s) pair per
// thread. The gather is 8192 scattered HBM cache lines -- spreading across
// 128 CUs overlaps the ~900-cycle miss latency instead of serializing it
// through one CU's miss queue (the R1 single-block design).
__global__ __launch_bounds__(64) void nll_partial_kernel(
    const float* __restrict__ out,    // [BS, V]
    const int*   __restrict__ tgt,    // [BS]
    float2* __restrict__ partials,    // [gridDim.x]
    int BS, int V)
{
    const int i = blockIdx.x * 64 + threadIdx.x;

    float sum = 0.0f;
    float cnt = 0.0f;
    if (i < BS) {
        const int t = tgt[i];
        if (t != MASK_IDX) {
            const float p = out[(long long)i * V + t];
            sum = -__builtin_logf(p);
            cnt = 1.0f;
        }
    }

    // 64-lane butterfly reduce (one wave per block, no LDS needed)
    #pragma unroll
    for (int off = 32; off > 0; off >>= 1) {
        sum += __shfl_down(sum, off, 64);
        cnt += __shfl_down(cnt, off, 64);
    }

    if (threadIdx.x == 0) {
        partials[blockIdx.x] = make_float2(sum, cnt);
    }
}

// Stage 2: one wave reduces the 128 partials and divides.
__global__ __launch_bounds__(64) void nll_final_kernel(
    const float2* __restrict__ partials,
    float* __restrict__ res,
    int nPart)
{
    float sum = 0.0f;
    float cnt = 0.0f;
    for (int j = threadIdx.x; j < nPart; j += 64) {
        const float2 p = partials[j];
        sum += p.x;
        cnt += p.y;
    }
    #pragma unroll
    for (int off = 32; off > 0; off >>= 1) {
        sum += __shfl_down(sum, off, 64);
        cnt += __shfl_down(cnt, off, 64);
    }
    if (threadIdx.x == 0) {
        res[0] = sum / cnt;
    }
}

extern "C" void kernel_launch(void* const* d_in, const int* in_sizes, int n_in,
                              void* d_out, int out_size, void* d_ws, size_t ws_size,
                              hipStream_t stream) {
    const float* out = (const float*)d_in[0];   // [B, S, V] fp32
    const int*   tgt = (const int*)d_in[1];     // [B, S] int32
    float* res = (float*)d_out;
    float2* partials = (float2*)d_ws;

    const int BS = in_sizes[1];                 // 16*512 = 8192
    const int V  = in_sizes[0] / in_sizes[1];   // 32000

    const int nBlocks = (BS + 63) / 64;         // 128

    nll_partial_kernel<<<nBlocks, 64, 0, stream>>>(out, tgt, partials, BS, V);
    nll_final_kernel<<<1, 64, 0, stream>>>(partials, res, nBlocks);
}